// Round 11
// baseline (1656.475 us; speedup 1.0000x reference)
//
#include <hip/hip_runtime.h>

typedef unsigned short u16;
typedef unsigned int u32;
typedef __attribute__((ext_vector_type(8))) short short8;
typedef __attribute__((ext_vector_type(4))) short short4v;
typedef __attribute__((ext_vector_type(4))) float float4v;
typedef _Float16 half8v __attribute__((ext_vector_type(8)));

static constexpr int   kN    = 100000;   // nodes
static constexpr int   kE    = 200000;   // edges
static constexpr int   kEMB  = 300;
static constexpr int   kSA   = 304;      // feature row stride (elems, u16)
static constexpr int   kNH   = 600;
static constexpr int   kG    = 5000;
static constexpr int   kL    = 5;
static constexpr float kEPS  = 1e-5f;

// ---- chunk-ordered weight images (1024B chunks, lane-contiguous) ----------
static constexpr int   kW1CL = 19 * 20 * 512;   // 194,560 u16 per layer
static constexpr int   kW2CL = 19 * 19 * 512;   // 184,832 u16 per layer

// ---- mlp LDS geometry (u16 units) — R6/R8-proven --------------------------
static constexpr int   kB1BUF = 10240;   // u16 per B1 buffer (20 chunks)
static constexpr int   kB2OFF = 20480;   // u16 offset of B2 region
static constexpr int   kB2BUF = 9728;    // u16 per B2 buffer (19 chunks)
static constexpr int   kSMEMU = 39936;   // total u16 (79,872 B)

__device__ inline float bf2f(u16 u) {
    union { u32 u32v; float f; } v; v.u32v = ((u32)u) << 16; return v.f;
}
__device__ inline u16 f2bf(float f) {
    union { float f; u32 u; } v; v.f = f;
    u32 r = v.u + 0x7fff + ((v.u >> 16) & 1);
    return (u16)(r >> 16);
}
__device__ inline float h2f(u16 u) {
    union { _Float16 h; u16 s; } v; v.s = u; return (float)v.h;
}
__device__ inline u16 f2h(float f) {           // f32 -> fp16 bits (RNE)
    union { _Float16 h; u16 s; } v; v.h = (_Float16)f; return v.s;
}
__device__ inline short8 load8(const u16* p) {
    return *reinterpret_cast<const short8*>(p);
}
__device__ inline half8v as_h8(short8 s) {
    union { short8 s; half8v h; } u; u.s = s; return u.h;
}
__device__ inline float4v zed4() { float4v z = {0.f, 0.f, 0.f, 0.f}; return z; }
__device__ inline float gload(const void* p, long long i, int isf32) {
    if (isf32) return ((const float*)p)[i];
    return bf2f(((const u16*)p)[i]);
}
// plane element decode/encode: enc=1 -> fp16 bits, enc=0 -> bf16 bits
__device__ inline float pcvt(short b, int enc) {
    return enc ? h2f((u16)b) : bf2f((u16)b);
}
__device__ inline short fenc(float v, int enc) {
    return (short)(enc ? f2h(v) : f2bf(v));
}
// direct global->LDS DMA, 16B per lane, dest = uniform base + lane*16
__device__ inline void gl_lds16(const void* g, void* l) {
    __builtin_amdgcn_global_load_lds(
        (__attribute__((address_space(1))) void*)g,
        (__attribute__((address_space(3))) void*)l, 16, 0, 0);
}

// ---- dtype detect: vote on W1 bit patterns --------------------------------
__global__ void detect_kernel(const u16* __restrict__ w1raw, int* flag) {
    if (threadIdx.x == 0 && blockIdx.x == 0) {
        int cnt = 0;
        for (int i = 0; i < 256; ++i) {
            int e = (w1raw[i] >> 7) & 0xFF;
            if (e >= 96 && e <= 126) ++cnt;
        }
        *flag = (cnt >= 200) ? 0 : 1;                // 0 = bf16 inputs, 1 = f32
    }
}

// ---- convert a float input to canonical f32 -------------------------------
__global__ void cvt_kernel(const void* __restrict__ src, float* __restrict__ dst,
                           int n, const int* __restrict__ flag) {
    int i = blockIdx.x * blockDim.x + threadIdx.x;
    if (i >= n) return;
    int isf = *flag;
    dst[i] = isf ? ((const float*)src)[i] : bf2f(((const u16*)src)[i]);
}

// ---- W1 -> chunk-ordered W1C (fp16 when enc else bf16) --------------------
__global__ void w1t_kernel(const void* __restrict__ W1, u16* __restrict__ W1C,
                           const int* __restrict__ flag, int enc) {
    int idx = blockIdx.x * blockDim.x + threadIdx.x;
    if (idx >= kL * kW1CL) return;
    int isf = *flag;
    int l = idx / kW1CL; int rem = idx - l * kW1CL;
    int p = rem / (20 * 512); int r2 = rem - p * (20 * 512);
    int c = r2 >> 9; int e = r2 & 511;
    int lane = e >> 3, j = e & 7;
    int hh = (c >= 10), kc = c - hh * 10;
    int n = p * 32 + hh * 16 + (lane & 15);
    int k = kc * 32 + (lane >> 4) * 8 + j;
    u16 v = 0;
    if (n < kNH && k < kEMB) {
        float f = gload(W1, (long long)l * kEMB * kNH + (long long)k * kNH + n, isf);
        v = enc ? f2h(f) : f2bf(f);
    }
    W1C[idx] = v;
}
// ---- W2 -> chunk-ordered W2C, a2-permuted k -------------------------------
__global__ void w2t_kernel(const void* __restrict__ W2, u16* __restrict__ W2C,
                           const int* __restrict__ flag, int enc) {
    int idx = blockIdx.x * blockDim.x + threadIdx.x;
    if (idx >= kL * kW2CL) return;
    int isf = *flag;
    int l = idx / kW2CL; int rem = idx - l * kW2CL;
    int p = rem / (19 * 512); int r2 = rem - p * (19 * 512);
    int nt2 = r2 >> 9; int e = r2 & 511;
    int lane = e >> 3, j = e & 7;
    int q = lane >> 4;
    int klocal = (j < 4) ? (q * 4 + j) : (16 + q * 4 + (j - 4));
    int k = p * 32 + klocal;
    int n = nt2 * 16 + (lane & 15);
    u16 v = 0;
    if (n < kEMB && k < kNH) {
        float f = gload(W2, (long long)l * kNH * kEMB + (long long)k * kEMB + n, isf);
        v = enc ? f2h(f) : f2bf(f);
    }
    W2C[idx] = v;
}

// ---- embedding (vectorized): 4 channels per thread -> short4 store --------
__global__ void embed_kernel(const int* __restrict__ x,
                             const float* __restrict__ emb1,
                             const float* __restrict__ emb2,
                             u16* __restrict__ h, int enc) {
    int idx = blockIdx.x * blockDim.x + threadIdx.x;
    if (idx >= kN * 76) return;
    int n = idx / 76, g = idx - n * 76;
    int cb = g * 4;
    short4v o = {0, 0, 0, 0};
    if (cb < kEMB) {
        float4v a = *reinterpret_cast<const float4v*>(emb1 + (size_t)x[2 * n] * kEMB + cb);
        float4v b = *reinterpret_cast<const float4v*>(emb2 + (size_t)x[2 * n + 1] * kEMB + cb);
#pragma unroll
        for (int jj = 0; jj < 4; ++jj) o[jj] = fenc(a[jj] + b[jj], enc);
    }
    *reinterpret_cast<short4v*>(h + (size_t)n * kSA + cb) = o;   // pad group -> 0
}

// ---- CSR build ------------------------------------------------------------
__global__ void zero_int_kernel(int* p, int n) {
    int i = blockIdx.x * blockDim.x + threadIdx.x;
    if (i < n) p[i] = 0;
}
__global__ void count_kernel(const int* __restrict__ dst, int* row_ptr) {
    int e = blockIdx.x * blockDim.x + threadIdx.x;
    if (e < kE) atomicAdd(&row_ptr[1 + dst[e]], 1);
}
__global__ __launch_bounds__(1024) void scan1_kernel(int* a, int* bsum, int n) {
    __shared__ int s[1024];
    int t = threadIdx.x;
    int i = blockIdx.x * 1024 + t;
    s[t] = (i < n) ? a[i] : 0;
    __syncthreads();
    for (int off = 1; off < 1024; off <<= 1) {
        int v = (t >= off) ? s[t - off] : 0;
        __syncthreads();
        s[t] += v;
        __syncthreads();
    }
    if (i < n) a[i] = s[t];
    if (t == 1023) bsum[blockIdx.x] = s[t];
}
__global__ __launch_bounds__(128) void scan2_kernel(const int* bsum, int* ebsum, int nb) {
    __shared__ int s[128];
    int t = threadIdx.x;
    int orig = (t < nb) ? bsum[t] : 0;
    s[t] = orig;
    __syncthreads();
    for (int off = 1; off < 128; off <<= 1) {
        int v = (t >= off) ? s[t - off] : 0;
        __syncthreads();
        s[t] += v;
        __syncthreads();
    }
    if (t < nb) ebsum[t] = s[t] - orig;   // exclusive
}
__global__ void scan3_kernel(int* a, const int* ebsum, int* row_ptr0, int n) {
    int i = blockIdx.x * blockDim.x + threadIdx.x;
    if (i >= n) return;
    a[i] += ebsum[i >> 10];
    if (i == 0) *row_ptr0 = 0;
}
__global__ void scatter_kernel(const int* __restrict__ src, const int* __restrict__ dst,
                               const int* __restrict__ ea,
                               const int* __restrict__ row_ptr, int* cursor,
                               int* __restrict__ epack) {
    int e = blockIdx.x * blockDim.x + threadIdx.x;
    if (e >= kE) return;
    int d = dst[e];
    int pos = row_ptr[d] + atomicAdd(&cursor[d], 1);
    epack[pos] = src[e] | (ea[2 * e] << 20) | (ea[2 * e + 1] << 24);
}

// ---- aggregation (vectorized gathers, edge-loop UNROLL x2 for ILP) --------
// Per iteration: 8 edge records + 8 row-gathers (16 load instrs) issued
// before any consumption -> ~2x in-flight HBM requests vs R10. Accumulation
// order per node is unchanged (i then i+1) -> numerics identical.
__global__ __launch_bounds__(256) void aggregate_kernel(
        const u16* __restrict__ h, const int* __restrict__ row_ptr,
        const int* __restrict__ epack,
        const float* __restrict__ e1,    // [6][kEMB] layer slice (f32)
        const float* __restrict__ e2,    // [3][kEMB]
        const float* __restrict__ stats_prev,  // prev layer stats (mode=1)
        const float* __restrict__ gam,         // prev layer gamma
        const float* __restrict__ bet,         // prev layer beta
        float* __restrict__ stats_next,        // zeroed here for next mlp
        u16* __restrict__ agg, int mode, int enc) {
    if (blockIdx.x == 0) {
        for (int i = threadIdx.x; i < 2 * kEMB; i += 256) stats_next[i] = 0.f;
    }
    int wave = threadIdx.x >> 6;
    int lane = threadIdx.x & 63;
    int base = (blockIdx.x * 4 + wave) * 4;          // 4 nodes per wave
    const short4v zs = {0, 0, 0, 0};

    float scv[2][4], shv[2][4];
#pragma unroll
    for (int j = 0; j < 2; ++j) {
#pragma unroll
        for (int jj = 0; jj < 4; ++jj) {
            int c = j * 256 + lane * 4 + jj;
            scv[j][jj] = 1.f; shv[j][jj] = 0.f;
            if (mode && c < kEMB) {
                const float invM = 1.0f / kN;
                float mu = stats_prev[c] * invM;
                float var = stats_prev[kEMB + c] * invM - mu * mu;
                if (var < 0.f) var = 0.f;
                float rs = rsqrtf(var + kEPS);
                scv[j][jj] = rs * gam[c];
                shv[j][jj] = bet[c] - mu * scv[j][jj];
            }
        }
    }

    int s[4], e[4];
    float acc[4][2][4];
#pragma unroll
    for (int t = 0; t < 4; ++t) {
        int node = base + t;
        if (node < kN) { s[t] = row_ptr[node]; e[t] = row_ptr[node + 1]; }
        else           { s[t] = 0; e[t] = 0; }
        short4v hv0 = zs, hv1 = zs;
        if (node < kN) {
            const u16* rp = h + (size_t)node * kSA;
            hv0 = *reinterpret_cast<const short4v*>(rp + lane * 4);
            if (lane < 12) hv1 = *reinterpret_cast<const short4v*>(rp + 256 + lane * 4);
        }
#pragma unroll
        for (int j = 0; j < 2; ++j) {
            int cb = j * 256 + lane * 4;
#pragma unroll
            for (int jj = 0; jj < 4; ++jj) acc[t][j][jj] = 0.f;
            if (node < kN && (j == 0 || lane < 11)) {
                float4v ev1 = *reinterpret_cast<const float4v*>(e1 + cb);
                float4v ev2 = *reinterpret_cast<const float4v*>(e2 + cb);
                short4v hv = j ? hv1 : hv0;
#pragma unroll
                for (int jj = 0; jj < 4; ++jj) {
                    float w = pcvt(hv[jj], enc) * scv[j][jj] + shv[j][jj];
                    if (mode && w < 0.f) w = 0.f;
                    acc[t][j][jj] = w + ev1[jj] + ev2[jj];   // self loop ea=(0,0)
                }
            }
        }
    }

    int maxd = 0;
#pragma unroll
    for (int t = 0; t < 4; ++t) {
        int d = e[t] - s[t];
        if (d > maxd) maxd = d;
    }

    for (int i = 0; i < maxd; i += 2) {
        int p[4][2], act[4][2];
#pragma unroll
        for (int t = 0; t < 4; ++t) {                // issue 8 edge-record loads
#pragma unroll
            for (int u = 0; u < 2; ++u) {
                act[t][u] = (s[t] + i + u < e[t]);
                p[t][u] = act[t][u] ? epack[s[t] + i + u] : 0;
            }
        }
        short4v hv[4][2][2];
#pragma unroll
        for (int t = 0; t < 4; ++t) {                // issue all 8 row-gathers
#pragma unroll
            for (int u = 0; u < 2; ++u) {
                hv[t][u][0] = zs; hv[t][u][1] = zs;
                if (act[t][u]) {
                    int srcn = p[t][u] & 0xFFFFF;
                    const u16* rp = h + (size_t)srcn * kSA;
                    hv[t][u][0] = *reinterpret_cast<const short4v*>(rp + lane * 4);
                    if (lane < 12)
                        hv[t][u][1] = *reinterpret_cast<const short4v*>(rp + 256 + lane * 4);
                }
            }
        }
#pragma unroll
        for (int t = 0; t < 4; ++t) {                // accumulate (i then i+1)
#pragma unroll
            for (int u = 0; u < 2; ++u) {
                if (act[t][u]) {
                    int a0 = (p[t][u] >> 20) & 15;
                    int a1 = (p[t][u] >> 24) & 15;
                    const float* e1p = e1 + a0 * kEMB;
                    const float* e2p = e2 + a1 * kEMB;
#pragma unroll
                    for (int j = 0; j < 2; ++j) {
                        int cb = j * 256 + lane * 4;
                        if (j == 0 || lane < 11) {
                            float4v ev1 = *reinterpret_cast<const float4v*>(e1p + cb);
                            float4v ev2 = *reinterpret_cast<const float4v*>(e2p + cb);
#pragma unroll
                            for (int jj = 0; jj < 4; ++jj) {
                                float w = pcvt(hv[t][u][j][jj], enc) * scv[j][jj] + shv[j][jj];
                                if (mode && w < 0.f) w = 0.f;
                                acc[t][j][jj] += w + ev1[jj] + ev2[jj];
                            }
                        }
                    }
                }
            }
        }
    }

#pragma unroll
    for (int t = 0; t < 4; ++t) {
        int node = base + t;
        if (node < kN) {
            u16* wp = agg + (size_t)node * kSA;
            short4v o;
#pragma unroll
            for (int jj = 0; jj < 4; ++jj) o[jj] = fenc(acc[t][0][jj], enc);
            *reinterpret_cast<short4v*>(wp + lane * 4) = o;
            if (lane < 12) {
#pragma unroll
                for (int jj = 0; jj < 4; ++jj) o[jj] = fenc(acc[t][1][jj], enc);
                *reinterpret_cast<short4v*>(wp + 256 + lane * 4) = o;  // lane11 -> 0 pad
            }
        }
    }
}

// ---- fused MLP + BN stats (R10-proven: R8 schedule + chunked DMA src) -----
template <int H16>
__global__ __launch_bounds__(256, 2) void mlp_kernel(
        const u16* A, u16* D,             // out-of-place (R6 dataflow)
        const u16* __restrict__ W1Cl,     // [19][20][512] chunk-ordered slice
        const float* __restrict__ bias1,  // [600] f32
        const u16* __restrict__ W2Cl,     // [19][19][512] chunk-ordered slice
        const float* __restrict__ bias2,  // [kEMB] f32
        float* __restrict__ stats) {      // [2][kEMB] zeroed by prior aggregate
    __shared__ __align__(16) u16 SMEM[kSMEMU];
    int tid = threadIdx.x;
    int wave = tid >> 6, lane = tid & 63;
    int r16 = lane & 15, quad = lane >> 4;
    const int NT = kN / 16;
    int mt_raw = blockIdx.x * 4 + wave;        // 1 m-tile per wave
    int mt = (mt_raw < NT) ? mt_raw : (NT - 1);
    int valid = (mt_raw < NT);

    // stage pair p1: every chunk is one contiguous 1024B burst from L2
    auto issue = [&](int p1) {
        u16* b1d = SMEM + (p1 & 1) * kB1BUF;
        u16* b2d = SMEM + kB2OFF + (p1 & 1) * kB2BUF;
        const u16* w1s = W1Cl + (size_t)p1 * (20 * 512) + lane * 8;
        const u16* w2s = W2Cl + (size_t)p1 * (19 * 512) + lane * 8;
#pragma unroll
        for (int i = 0; i < 10; ++i) {
            int c = wave + 4 * i;
            if (c < 20) {
                gl_lds16(w1s + c * 512, b1d + c * 512);
            } else if (c < 39) {
                int nt2 = c - 20;
                gl_lds16(w2s + nt2 * 512, b2d + nt2 * 512);
            }
        }
    };

    issue(0);   // prologue: pair 0 -> buffers[0]

    short8 ahi[10];
    short8 zed = {0, 0, 0, 0, 0, 0, 0, 0};
    {
        const u16* Arow = A + (size_t)(mt * 16 + r16) * kSA + quad * 8;
#pragma unroll
        for (int kc = 0; kc < 9; ++kc) ahi[kc] = load8(Arow + kc * 32);
        ahi[9] = (quad < 2) ? load8(Arow + 9 * 32) : zed;
    }

    float4v acc2[19];
#pragma unroll
    for (int i = 0; i < 19; ++i) acc2[i] = zed4();

    short8 a2 = zed;        // h1 fragment (fp16 or bf16-hi), filled per pair
    short8 a2l = zed;       // bf16-lo (H16=0 only)

    for (int p = 0; p < 19; ++p) {
        __syncthreads();    // drains pair-p DMA; fences prior readers
        if (p + 1 < 19) issue(p + 1);

        const u16* B1 = SMEM + (p & 1) * kB1BUF;
        const u16* B2 = SMEM + kB2OFF + (p & 1) * kB2BUF;

#pragma unroll
        for (int hh = 0; hh < 2; ++hh) {
            const u16* bb = B1 + hh * 10 * 512;
            float4v aa = zed4(), ab = zed4();
#pragma unroll
            for (int kc = 0; kc < 10; kc += 2) {
                short8 w0 = load8(bb + kc * 512 + lane * 8);
                short8 w1 = load8(bb + (kc + 1) * 512 + lane * 8);
                if (H16) {
                    aa = __builtin_amdgcn_mfma_f32_16x16x32_f16(as_h8(w0), as_h8(ahi[kc]), aa, 0, 0, 0);
                    ab = __builtin_amdgcn_mfma_f32_16x16x32_f16(as_h8(w1), as_h8(ahi[kc + 1]), ab, 0, 0, 0);
                } else {
                    aa = __builtin_amdgcn_mfma_f32_16x16x32_bf16(w0, ahi[kc], aa, 0, 0, 0);
                    ab = __builtin_amdgcn_mfma_f32_16x16x32_bf16(w1, ahi[kc + 1], ab, 0, 0, 0);
                }
            }
            float4v bv = *(const float4v*)(bias1 + (2 * p + hh) * 16 + quad * 4);
#pragma unroll
            for (int r = 0; r < 4; ++r) {
                int n1 = (2 * p + hh) * 16 + quad * 4 + r;
                float v = (n1 < kNH) ? (aa[r] + ab[r] + bv[r]) : 0.f;
                if (v < 0.f) v = 0.f;
                if (H16) {
                    a2[hh * 4 + r] = (short)f2h(v);
                } else {
                    u16 hb = f2bf(v);
                    a2[hh * 4 + r] = (short)hb;
                    a2l[hh * 4 + r] = (short)f2bf(v - bf2f(hb));
                }
            }
        }

#pragma unroll
        for (int nt2 = 0; nt2 < 19; ++nt2) {
            short8 b = load8(B2 + nt2 * 512 + lane * 8);
            if (H16) {
                acc2[nt2] = __builtin_amdgcn_mfma_f32_16x16x32_f16(as_h8(a2), as_h8(b), acc2[nt2], 0, 0, 0);
            } else {
                acc2[nt2] = __builtin_amdgcn_mfma_f32_16x16x32_bf16(a2, b, acc2[nt2], 0, 0, 0);
                acc2[nt2] = __builtin_amdgcn_mfma_f32_16x16x32_bf16(a2l, b, acc2[nt2], 0, 0, 0);
            }
        }
    }

    // ---- epilogue: +bias2 -> D; block-level BN stat reduction ----
    __syncthreads();                 // all waves done reading SMEM buffers
    float* RB = (float*)SMEM;        // reuse: needs 2*4*304 floats (9,728 B)
#pragma unroll
    for (int nt2 = 0; nt2 < 19; ++nt2) {
        int n = nt2 * 16 + r16;
        float s4 = 0.f, q4 = 0.f;
        if (valid && n < kEMB) {
            float bv = bias2[n];
#pragma unroll
            for (int r = 0; r < 4; ++r) {
                float v = acc2[nt2][r] + bv;
                int m = mt * 16 + quad * 4 + r;
                D[(size_t)m * kSA + n] = (u16)(H16 ? f2h(v) : f2bf(v));
                s4 += v; q4 += v * v;
            }
        }
        s4 += __shfl_down(s4, 32); q4 += __shfl_down(q4, 32);
        s4 += __shfl_down(s4, 16); q4 += __shfl_down(q4, 16);
        if (quad == 0) {
            RB[wave * 304 + nt2 * 16 + r16] = s4;
            RB[1216 + wave * 304 + nt2 * 16 + r16] = q4;
        }
    }
    __syncthreads();
    for (int c = tid; c < 304; c += 256) {
        if (c < kEMB) {
            float ss = 0.f, qq = 0.f;
#pragma unroll
            for (int w = 0; w < 4; ++w) {
                ss += RB[w * 304 + c];
                qq += RB[1216 + w * 304 + c];
            }
            atomicAdd(&stats[c], ss);
            atomicAdd(&stats[kEMB + c], qq);
        }
    }
}

// ---- per-graph mean pool (vectorized) with fused final BN -----------------
__device__ inline int lower_bound(const int* a, int n, int key) {
    int lo = 0, hi = n;
    while (lo < hi) { int mid = (lo + hi) >> 1; if (a[mid] < key) lo = mid + 1; else hi = mid; }
    return lo;
}
__global__ __launch_bounds__(64) void pool_kernel(const u16* __restrict__ h2,
                                                  const int* __restrict__ batch,
                                                  const float* __restrict__ stats,
                                                  const float* __restrict__ gam,
                                                  const float* __restrict__ bet,
                                                  void* __restrict__ out,
                                                  const int* __restrict__ flag, int enc) {
    int g = blockIdx.x;
    int lane = threadIdx.x;
    int isf = *flag;
    int start = lower_bound(batch, kN, g);
    int end = lower_bound(batch, kN, g + 1);
    int cnt = end - start;
    float inv = 1.0f / (float)(cnt > 0 ? cnt : 1);
    const float invM = 1.0f / kN;
    for (int cg = lane; cg < 75; cg += 64) {        // 4 channels per group
        int cb = cg * 4;
        float sc[4], sh[4];
#pragma unroll
        for (int jj = 0; jj < 4; ++jj) {
            int c = cb + jj;
            float mu = stats[c] * invM;
            float var = stats[kEMB + c] * invM - mu * mu;
            if (var < 0.f) var = 0.f;
            float rs = rsqrtf(var + kEPS);
            sc[jj] = rs * gam[c];
            sh[jj] = bet[c] - mu * sc[jj];
        }
        float s[4] = {0.f, 0.f, 0.f, 0.f};
        for (int n = start; n < end; ++n) {
            short4v v = *reinterpret_cast<const short4v*>(h2 + (size_t)n * kSA + cb);
#pragma unroll
            for (int jj = 0; jj < 4; ++jj)
                s[jj] += pcvt(v[jj], enc) * sc[jj] + sh[jj];
        }
        if (isf) {
            float4v o;
#pragma unroll
            for (int jj = 0; jj < 4; ++jj) o[jj] = s[jj] * inv;
            *reinterpret_cast<float4v*>((float*)out + (size_t)g * kEMB + cb) = o;
        } else {
            short4v o;
#pragma unroll
            for (int jj = 0; jj < 4; ++jj) o[jj] = (short)f2bf(s[jj] * inv);
            *reinterpret_cast<short4v*>((u16*)out + (size_t)g * kEMB + cb) = o;
        }
    }
}

// ===========================================================================
extern "C" void kernel_launch(void* const* d_in, const int* in_sizes, int n_in,
                              void* d_out, int out_size, void* d_ws, size_t ws_size,
                              hipStream_t stream) {
    const int* x          = (const int*)d_in[0];
    const int* edge_index = (const int*)d_in[1];
    const int* edge_attr  = (const int*)d_in[2];
    const int* batch      = (const int*)d_in[3];
    const void* x_emb1 = d_in[4];
    const void* x_emb2 = d_in[5];
    const void* e1raw  = d_in[6];
    const void* e2raw  = d_in[7];
    const void* W1     = d_in[8];
    const void* b1raw  = d_in[9];
    const void* W2     = d_in[10];
    const void* b2raw  = d_in[11];
    const void* gmraw  = d_in[12];
    const void* btraw  = d_in[13];

    const int* src = edge_index;
    const int* dst = edge_index + kE;

    // Plane encoding: big ws (f32 inputs) -> fp16 planes; else bf16 planes.
    const int enc = (ws_size >= (size_t)250000000) ? 1 : 0;

    // ---- carve workspace (256B aligned) ----
    char* p = (char*)d_ws;
    size_t off = 0;
    auto carve = [&](size_t bytes) {
        void* r = p + off;
        off += (bytes + 255) & ~(size_t)255;
        return r;
    };
    u16* plane0  = (u16*)carve((size_t)kN * kSA * 2);
    u16* plane1  = (u16*)carve((size_t)kN * kSA * 2);
    u16* W1C     = (u16*)carve((size_t)kL * kW1CL * 2);
    u16* W2C     = (u16*)carve((size_t)kL * kW2CL * 2);
    int* row_ptr = (int*)carve((size_t)(kN + 1) * 4);
    int* cursor  = (int*)carve((size_t)kN * 4);
    int* epack   = (int*)carve((size_t)kE * 4);
    float* statsA = (float*)carve(2 * kEMB * 4);
    float* statsB = (float*)carve(2 * kEMB * 4);
    int* bsum    = (int*)carve(512);
    int* ebsum   = (int*)carve(512);
    int* flag    = (int*)carve(256);
    float* parf  = (float*)carve((size_t)57900 * 4);   // canonical f32 params

    float* emb1  = parf + 0;       // 36000
    float* emb2  = parf + 36000;   // 900
    float* e1    = parf + 36900;   // 9000
    float* e2    = parf + 45900;   // 4500
    float* b1    = parf + 50400;   // 3000
    float* b2    = parf + 53400;   // 1500
    float* gamma = parf + 54900;   // 1500
    float* beta  = parf + 56400;   // 1500

    // ---- dtype detect + canonicalize params to f32 ----
    detect_kernel<<<1, 64, 0, stream>>>((const u16*)W1, flag);
    cvt_kernel<<<(36000 + 255) / 256, 256, 0, stream>>>(x_emb1, emb1, 36000, flag);
    cvt_kernel<<<(900 + 255) / 256, 256, 0, stream>>>(x_emb2, emb2, 900, flag);
    cvt_kernel<<<(9000 + 255) / 256, 256, 0, stream>>>(e1raw, e1, 9000, flag);
    cvt_kernel<<<(4500 + 255) / 256, 256, 0, stream>>>(e2raw, e2, 4500, flag);
    cvt_kernel<<<(3000 + 255) / 256, 256, 0, stream>>>(b1raw, b1, 3000, flag);
    cvt_kernel<<<(1500 + 255) / 256, 256, 0, stream>>>(b2raw, b2, 1500, flag);
    cvt_kernel<<<(1500 + 255) / 256, 256, 0, stream>>>(gmraw, gamma, 1500, flag);
    cvt_kernel<<<(1500 + 255) / 256, 256, 0, stream>>>(btraw, beta, 1500, flag);

    // ---- weight repack to chunk order (fp16 when enc, else bf16) ----
    {
        int n1 = kL * kW1CL;
        w1t_kernel<<<(n1 + 255) / 256, 256, 0, stream>>>(W1, W1C, flag, enc);
        int n2 = kL * kW2CL;
        w2t_kernel<<<(n2 + 255) / 256, 256, 0, stream>>>(W2, W2C, flag, enc);
    }

    // ---- embedding into plane0 (vectorized) ----
    embed_kernel<<<(kN * 76 + 255) / 256, 256, 0, stream>>>(x, emb1, emb2, plane0, enc);

    // ---- CSR build (multi-block scan) ----
    zero_int_kernel<<<(kN + 1 + 255) / 256, 256, 0, stream>>>(row_ptr, kN + 1);
    zero_int_kernel<<<(kN + 255) / 256, 256, 0, stream>>>(cursor, kN);
    count_kernel<<<(kE + 255) / 256, 256, 0, stream>>>(dst, row_ptr);
    const int nb = (kN + 1023) / 1024;   // 98
    scan1_kernel<<<nb, 1024, 0, stream>>>(row_ptr + 1, bsum, kN);
    scan2_kernel<<<1, 128, 0, stream>>>(bsum, ebsum, nb);
    scan3_kernel<<<(kN + 255) / 256, 256, 0, stream>>>(row_ptr + 1, ebsum, row_ptr, kN);
    scatter_kernel<<<(kE + 255) / 256, 256, 0, stream>>>(src, dst, edge_attr, row_ptr,
                                                         cursor, epack);

    // ---- layers: aggregate(cur -> oth), mlp(oth -> cur) ----
    const int mlp_blocks = (kN / 16 + 3) / 4;   // 1563 (4 m-tiles per block)
    const int agg_blocks = (kN + 15) / 16;      // 6250 (16 nodes per block)
    u16* cur = plane0;
    u16* oth = plane1;
    float* stats_prev = statsA;   // unused at l=0
    for (int l = 0; l < kL; ++l) {
        float* stats_cur = (l % 2 == 0) ? statsA : statsB;
        const float* gam_prev = gamma + (l > 0 ? (l - 1) : 0) * kEMB;
        const float* bet_prev = beta + (l > 0 ? (l - 1) : 0) * kEMB;
        aggregate_kernel<<<agg_blocks, 256, 0, stream>>>(
            cur, row_ptr, epack, e1 + l * 6 * kEMB, e2 + l * 3 * kEMB,
            (l > 0) ? stats_prev : stats_cur, gam_prev, bet_prev,
            stats_cur, oth, (l > 0) ? 1 : 0, enc);
        if (enc)
            mlp_kernel<1><<<mlp_blocks, 256, 0, stream>>>(
                oth, cur, W1C + (size_t)l * kW1CL, b1 + l * kNH,
                W2C + (size_t)l * kW2CL, b2 + l * kEMB, stats_cur);
        else
            mlp_kernel<0><<<mlp_blocks, 256, 0, stream>>>(
                oth, cur, W1C + (size_t)l * kW1CL, b1 + l * kNH,
                W2C + (size_t)l * kW2CL, b2 + l * kEMB, stats_cur);
        stats_prev = stats_cur;
    }

    // ---- pooling with fused final BN (stats_prev = layer 4's stats) ----
    pool_kernel<<<kG, 64, 0, stream>>>(cur, batch, stats_prev, gamma + 4 * kEMB,
                                       beta + 4 * kEMB, d_out, flag, enc);
}

// Round 12
// 1569.720 us; speedup vs baseline: 1.0553x; 1.0553x over previous
//
#include <hip/hip_runtime.h>

typedef unsigned short u16;
typedef unsigned int u32;
typedef __attribute__((ext_vector_type(8))) short short8;
typedef __attribute__((ext_vector_type(4))) short short4v;
typedef __attribute__((ext_vector_type(4))) float float4v;
typedef _Float16 half8v __attribute__((ext_vector_type(8)));

static constexpr int   kN    = 100000;   // nodes
static constexpr int   kE    = 200000;   // edges
static constexpr int   kEMB  = 300;
static constexpr int   kSA   = 304;      // feature row stride (elems, u16)
static constexpr int   kNH   = 600;
static constexpr int   kG    = 5000;
static constexpr int   kL    = 5;
static constexpr float kEPS  = 1e-5f;

// ---- chunk-ordered weight images (1024B chunks, lane-contiguous) ----------
static constexpr int   kW1CL = 19 * 20 * 512;   // 194,560 u16 per layer
static constexpr int   kW2CL = 19 * 19 * 512;   // 184,832 u16 per layer

// ---- mlp LDS geometry (u16 units) — R6/R8-proven --------------------------
static constexpr int   kB1BUF = 10240;   // u16 per B1 buffer (20 chunks)
static constexpr int   kB2OFF = 20480;   // u16 offset of B2 region
static constexpr int   kB2BUF = 9728;    // u16 per B2 buffer (19 chunks)
static constexpr int   kSMEMU = 39936;   // total u16 (79,872 B)

__device__ inline float bf2f(u16 u) {
    union { u32 u32v; float f; } v; v.u32v = ((u32)u) << 16; return v.f;
}
__device__ inline u16 f2bf(float f) {
    union { float f; u32 u; } v; v.f = f;
    u32 r = v.u + 0x7fff + ((v.u >> 16) & 1);
    return (u16)(r >> 16);
}
__device__ inline float h2f(u16 u) {
    union { _Float16 h; u16 s; } v; v.s = u; return (float)v.h;
}
__device__ inline u16 f2h(float f) {           // f32 -> fp16 bits (RNE)
    union { _Float16 h; u16 s; } v; v.h = (_Float16)f; return v.s;
}
__device__ inline short8 load8(const u16* p) {
    return *reinterpret_cast<const short8*>(p);
}
__device__ inline half8v as_h8(short8 s) {
    union { short8 s; half8v h; } u; u.s = s; return u.h;
}
__device__ inline float4v zed4() { float4v z = {0.f, 0.f, 0.f, 0.f}; return z; }
__device__ inline float gload(const void* p, long long i, int isf32) {
    if (isf32) return ((const float*)p)[i];
    return bf2f(((const u16*)p)[i]);
}
// plane element decode/encode: enc=1 -> fp16 bits, enc=0 -> bf16 bits
__device__ inline float pcvt(short b, int enc) {
    return enc ? h2f((u16)b) : bf2f((u16)b);
}
__device__ inline short fenc(float v, int enc) {
    return (short)(enc ? f2h(v) : f2bf(v));
}
// direct global->LDS DMA, 16B per lane, dest = uniform base + lane*16
__device__ inline void gl_lds16(const void* g, void* l) {
    __builtin_amdgcn_global_load_lds(
        (__attribute__((address_space(1))) void*)g,
        (__attribute__((address_space(3))) void*)l, 16, 0, 0);
}

// ---- dtype detect: vote on W1 bit patterns --------------------------------
__global__ void detect_kernel(const u16* __restrict__ w1raw, int* flag) {
    if (threadIdx.x == 0 && blockIdx.x == 0) {
        int cnt = 0;
        for (int i = 0; i < 256; ++i) {
            int e = (w1raw[i] >> 7) & 0xFF;
            if (e >= 96 && e <= 126) ++cnt;
        }
        *flag = (cnt >= 200) ? 0 : 1;                // 0 = bf16 inputs, 1 = f32
    }
}

// ---- convert a float input to canonical f32 -------------------------------
__global__ void cvt_kernel(const void* __restrict__ src, float* __restrict__ dst,
                           int n, const int* __restrict__ flag) {
    int i = blockIdx.x * blockDim.x + threadIdx.x;
    if (i >= n) return;
    int isf = *flag;
    dst[i] = isf ? ((const float*)src)[i] : bf2f(((const u16*)src)[i]);
}

// ---- W1 -> chunk-ordered W1C (fp16 when enc else bf16) --------------------
__global__ void w1t_kernel(const void* __restrict__ W1, u16* __restrict__ W1C,
                           const int* __restrict__ flag, int enc) {
    int idx = blockIdx.x * blockDim.x + threadIdx.x;
    if (idx >= kL * kW1CL) return;
    int isf = *flag;
    int l = idx / kW1CL; int rem = idx - l * kW1CL;
    int p = rem / (20 * 512); int r2 = rem - p * (20 * 512);
    int c = r2 >> 9; int e = r2 & 511;
    int lane = e >> 3, j = e & 7;
    int hh = (c >= 10), kc = c - hh * 10;
    int n = p * 32 + hh * 16 + (lane & 15);
    int k = kc * 32 + (lane >> 4) * 8 + j;
    u16 v = 0;
    if (n < kNH && k < kEMB) {
        float f = gload(W1, (long long)l * kEMB * kNH + (long long)k * kNH + n, isf);
        v = enc ? f2h(f) : f2bf(f);
    }
    W1C[idx] = v;
}
// ---- W2 -> chunk-ordered W2C, a2-permuted k -------------------------------
__global__ void w2t_kernel(const void* __restrict__ W2, u16* __restrict__ W2C,
                           const int* __restrict__ flag, int enc) {
    int idx = blockIdx.x * blockDim.x + threadIdx.x;
    if (idx >= kL * kW2CL) return;
    int isf = *flag;
    int l = idx / kW2CL; int rem = idx - l * kW2CL;
    int p = rem / (19 * 512); int r2 = rem - p * (19 * 512);
    int nt2 = r2 >> 9; int e = r2 & 511;
    int lane = e >> 3, j = e & 7;
    int q = lane >> 4;
    int klocal = (j < 4) ? (q * 4 + j) : (16 + q * 4 + (j - 4));
    int k = p * 32 + klocal;
    int n = nt2 * 16 + (lane & 15);
    u16 v = 0;
    if (n < kEMB && k < kNH) {
        float f = gload(W2, (long long)l * kNH * kEMB + (long long)k * kEMB + n, isf);
        v = enc ? f2h(f) : f2bf(f);
    }
    W2C[idx] = v;
}

// ---- embedding (vectorized): 4 channels per thread -> short4 store --------
__global__ void embed_kernel(const int* __restrict__ x,
                             const float* __restrict__ emb1,
                             const float* __restrict__ emb2,
                             u16* __restrict__ h, int enc) {
    int idx = blockIdx.x * blockDim.x + threadIdx.x;
    if (idx >= kN * 76) return;
    int n = idx / 76, g = idx - n * 76;
    int cb = g * 4;
    short4v o = {0, 0, 0, 0};
    if (cb < kEMB) {
        float4v a = *reinterpret_cast<const float4v*>(emb1 + (size_t)x[2 * n] * kEMB + cb);
        float4v b = *reinterpret_cast<const float4v*>(emb2 + (size_t)x[2 * n + 1] * kEMB + cb);
#pragma unroll
        for (int jj = 0; jj < 4; ++jj) o[jj] = fenc(a[jj] + b[jj], enc);
    }
    *reinterpret_cast<short4v*>(h + (size_t)n * kSA + cb) = o;   // pad group -> 0
}

// ---- CSR build ------------------------------------------------------------
__global__ void zero_int_kernel(int* p, int n) {
    int i = blockIdx.x * blockDim.x + threadIdx.x;
    if (i < n) p[i] = 0;
}
__global__ void count_kernel(const int* __restrict__ dst, int* row_ptr) {
    int e = blockIdx.x * blockDim.x + threadIdx.x;
    if (e < kE) atomicAdd(&row_ptr[1 + dst[e]], 1);
}
__global__ __launch_bounds__(1024) void scan1_kernel(int* a, int* bsum, int n) {
    __shared__ int s[1024];
    int t = threadIdx.x;
    int i = blockIdx.x * 1024 + t;
    s[t] = (i < n) ? a[i] : 0;
    __syncthreads();
    for (int off = 1; off < 1024; off <<= 1) {
        int v = (t >= off) ? s[t - off] : 0;
        __syncthreads();
        s[t] += v;
        __syncthreads();
    }
    if (i < n) a[i] = s[t];
    if (t == 1023) bsum[blockIdx.x] = s[t];
}
__global__ __launch_bounds__(128) void scan2_kernel(const int* bsum, int* ebsum, int nb) {
    __shared__ int s[128];
    int t = threadIdx.x;
    int orig = (t < nb) ? bsum[t] : 0;
    s[t] = orig;
    __syncthreads();
    for (int off = 1; off < 128; off <<= 1) {
        int v = (t >= off) ? s[t - off] : 0;
        __syncthreads();
        s[t] += v;
        __syncthreads();
    }
    if (t < nb) ebsum[t] = s[t] - orig;   // exclusive
}
__global__ void scan3_kernel(int* a, const int* ebsum, int* row_ptr0, int n) {
    int i = blockIdx.x * blockDim.x + threadIdx.x;
    if (i >= n) return;
    a[i] += ebsum[i >> 10];
    if (i == 0) *row_ptr0 = 0;
}
__global__ void scatter_kernel(const int* __restrict__ src, const int* __restrict__ dst,
                               const int* __restrict__ ea,
                               const int* __restrict__ row_ptr, int* cursor,
                               int* __restrict__ epack) {
    int e = blockIdx.x * blockDim.x + threadIdx.x;
    if (e >= kE) return;
    int d = dst[e];
    int pos = row_ptr[d] + atomicAdd(&cursor[d], 1);
    epack[pos] = src[e] | (ea[2 * e] << 20) | (ea[2 * e + 1] << 24);
}

// ---- aggregation (vectorized gathers), 4 NODES PER WAVE, fused BN ---------
// R10-proven form (the R11 unroll x2 regressed: +32 VGPR live state and
// even-rounded edge loops cost more than the extra gather depth bought).
__global__ __launch_bounds__(256) void aggregate_kernel(
        const u16* __restrict__ h, const int* __restrict__ row_ptr,
        const int* __restrict__ epack,
        const float* __restrict__ e1,    // [6][kEMB] layer slice (f32)
        const float* __restrict__ e2,    // [3][kEMB]
        const float* __restrict__ stats_prev,  // prev layer stats (mode=1)
        const float* __restrict__ gam,         // prev layer gamma
        const float* __restrict__ bet,         // prev layer beta
        float* __restrict__ stats_next,        // zeroed here for next mlp
        u16* __restrict__ agg, int mode, int enc) {
    if (blockIdx.x == 0) {
        for (int i = threadIdx.x; i < 2 * kEMB; i += 256) stats_next[i] = 0.f;
    }
    int wave = threadIdx.x >> 6;
    int lane = threadIdx.x & 63;
    int base = (blockIdx.x * 4 + wave) * 4;          // 4 nodes per wave
    const short4v zs = {0, 0, 0, 0};

    float scv[2][4], shv[2][4];
#pragma unroll
    for (int j = 0; j < 2; ++j) {
#pragma unroll
        for (int jj = 0; jj < 4; ++jj) {
            int c = j * 256 + lane * 4 + jj;
            scv[j][jj] = 1.f; shv[j][jj] = 0.f;
            if (mode && c < kEMB) {
                const float invM = 1.0f / kN;
                float mu = stats_prev[c] * invM;
                float var = stats_prev[kEMB + c] * invM - mu * mu;
                if (var < 0.f) var = 0.f;
                float rs = rsqrtf(var + kEPS);
                scv[j][jj] = rs * gam[c];
                shv[j][jj] = bet[c] - mu * scv[j][jj];
            }
        }
    }

    int s[4], e[4];
    float acc[4][2][4];
#pragma unroll
    for (int t = 0; t < 4; ++t) {
        int node = base + t;
        if (node < kN) { s[t] = row_ptr[node]; e[t] = row_ptr[node + 1]; }
        else           { s[t] = 0; e[t] = 0; }
        short4v hv0 = zs, hv1 = zs;
        if (node < kN) {
            const u16* rp = h + (size_t)node * kSA;
            hv0 = *reinterpret_cast<const short4v*>(rp + lane * 4);
            if (lane < 12) hv1 = *reinterpret_cast<const short4v*>(rp + 256 + lane * 4);
        }
#pragma unroll
        for (int j = 0; j < 2; ++j) {
            int cb = j * 256 + lane * 4;
#pragma unroll
            for (int jj = 0; jj < 4; ++jj) acc[t][j][jj] = 0.f;
            if (node < kN && (j == 0 || lane < 11)) {
                float4v ev1 = *reinterpret_cast<const float4v*>(e1 + cb);
                float4v ev2 = *reinterpret_cast<const float4v*>(e2 + cb);
                short4v hv = j ? hv1 : hv0;
#pragma unroll
                for (int jj = 0; jj < 4; ++jj) {
                    float w = pcvt(hv[jj], enc) * scv[j][jj] + shv[j][jj];
                    if (mode && w < 0.f) w = 0.f;
                    acc[t][j][jj] = w + ev1[jj] + ev2[jj];   // self loop ea=(0,0)
                }
            }
        }
    }

    int maxd = 0;
#pragma unroll
    for (int t = 0; t < 4; ++t) {
        int d = e[t] - s[t];
        if (d > maxd) maxd = d;
    }

    for (int i = 0; i < maxd; ++i) {
        int p[4], act[4];
#pragma unroll
        for (int t = 0; t < 4; ++t) {                // issue edge-record loads
            act[t] = (s[t] + i < e[t]);
            p[t] = act[t] ? epack[s[t] + i] : 0;
        }
        short4v hv[4][2];
#pragma unroll
        for (int t = 0; t < 4; ++t) {                // issue all gathers
            hv[t][0] = zs; hv[t][1] = zs;
            if (act[t]) {
                int srcn = p[t] & 0xFFFFF;
                const u16* rp = h + (size_t)srcn * kSA;
                hv[t][0] = *reinterpret_cast<const short4v*>(rp + lane * 4);
                if (lane < 12)
                    hv[t][1] = *reinterpret_cast<const short4v*>(rp + 256 + lane * 4);
            }
        }
#pragma unroll
        for (int t = 0; t < 4; ++t) {                // accumulate
            if (act[t]) {
                int a0 = (p[t] >> 20) & 15;
                int a1 = (p[t] >> 24) & 15;
                const float* e1p = e1 + a0 * kEMB;
                const float* e2p = e2 + a1 * kEMB;
#pragma unroll
                for (int j = 0; j < 2; ++j) {
                    int cb = j * 256 + lane * 4;
                    if (j == 0 || lane < 11) {
                        float4v ev1 = *reinterpret_cast<const float4v*>(e1p + cb);
                        float4v ev2 = *reinterpret_cast<const float4v*>(e2p + cb);
#pragma unroll
                        for (int jj = 0; jj < 4; ++jj) {
                            float w = pcvt(hv[t][j][jj], enc) * scv[j][jj] + shv[j][jj];
                            if (mode && w < 0.f) w = 0.f;
                            acc[t][j][jj] += w + ev1[jj] + ev2[jj];
                        }
                    }
                }
            }
        }
    }

#pragma unroll
    for (int t = 0; t < 4; ++t) {
        int node = base + t;
        if (node < kN) {
            u16* wp = agg + (size_t)node * kSA;
            short4v o;
#pragma unroll
            for (int jj = 0; jj < 4; ++jj) o[jj] = fenc(acc[t][0][jj], enc);
            *reinterpret_cast<short4v*>(wp + lane * 4) = o;
            if (lane < 12) {
#pragma unroll
                for (int jj = 0; jj < 4; ++jj) o[jj] = fenc(acc[t][1][jj], enc);
                *reinterpret_cast<short4v*>(wp + 256 + lane * 4) = o;  // lane11 -> 0 pad
            }
        }
    }
}

// ---- fused MLP + BN stats (R10-proven: R8 schedule + chunked DMA src) -----
template <int H16>
__global__ __launch_bounds__(256, 2) void mlp_kernel(
        const u16* A, u16* D,             // out-of-place (R6 dataflow)
        const u16* __restrict__ W1Cl,     // [19][20][512] chunk-ordered slice
        const float* __restrict__ bias1,  // [600] f32
        const u16* __restrict__ W2Cl,     // [19][19][512] chunk-ordered slice
        const float* __restrict__ bias2,  // [kEMB] f32
        float* __restrict__ stats) {      // [2][kEMB] zeroed by prior aggregate
    __shared__ __align__(16) u16 SMEM[kSMEMU];
    int tid = threadIdx.x;
    int wave = tid >> 6, lane = tid & 63;
    int r16 = lane & 15, quad = lane >> 4;
    const int NT = kN / 16;
    int mt_raw = blockIdx.x * 4 + wave;        // 1 m-tile per wave
    int mt = (mt_raw < NT) ? mt_raw : (NT - 1);
    int valid = (mt_raw < NT);

    // stage pair p1: every chunk is one contiguous 1024B burst from L2
    auto issue = [&](int p1) {
        u16* b1d = SMEM + (p1 & 1) * kB1BUF;
        u16* b2d = SMEM + kB2OFF + (p1 & 1) * kB2BUF;
        const u16* w1s = W1Cl + (size_t)p1 * (20 * 512) + lane * 8;
        const u16* w2s = W2Cl + (size_t)p1 * (19 * 512) + lane * 8;
#pragma unroll
        for (int i = 0; i < 10; ++i) {
            int c = wave + 4 * i;
            if (c < 20) {
                gl_lds16(w1s + c * 512, b1d + c * 512);
            } else if (c < 39) {
                int nt2 = c - 20;
                gl_lds16(w2s + nt2 * 512, b2d + nt2 * 512);
            }
        }
    };

    issue(0);   // prologue: pair 0 -> buffers[0]

    short8 ahi[10];
    short8 zed = {0, 0, 0, 0, 0, 0, 0, 0};
    {
        const u16* Arow = A + (size_t)(mt * 16 + r16) * kSA + quad * 8;
#pragma unroll
        for (int kc = 0; kc < 9; ++kc) ahi[kc] = load8(Arow + kc * 32);
        ahi[9] = (quad < 2) ? load8(Arow + 9 * 32) : zed;
    }

    float4v acc2[19];
#pragma unroll
    for (int i = 0; i < 19; ++i) acc2[i] = zed4();

    short8 a2 = zed;        // h1 fragment (fp16 or bf16-hi), filled per pair
    short8 a2l = zed;       // bf16-lo (H16=0 only)

    for (int p = 0; p < 19; ++p) {
        __syncthreads();    // drains pair-p DMA; fences prior readers
        if (p + 1 < 19) issue(p + 1);

        const u16* B1 = SMEM + (p & 1) * kB1BUF;
        const u16* B2 = SMEM + kB2OFF + (p & 1) * kB2BUF;

#pragma unroll
        for (int hh = 0; hh < 2; ++hh) {
            const u16* bb = B1 + hh * 10 * 512;
            float4v aa = zed4(), ab = zed4();
#pragma unroll
            for (int kc = 0; kc < 10; kc += 2) {
                short8 w0 = load8(bb + kc * 512 + lane * 8);
                short8 w1 = load8(bb + (kc + 1) * 512 + lane * 8);
                if (H16) {
                    aa = __builtin_amdgcn_mfma_f32_16x16x32_f16(as_h8(w0), as_h8(ahi[kc]), aa, 0, 0, 0);
                    ab = __builtin_amdgcn_mfma_f32_16x16x32_f16(as_h8(w1), as_h8(ahi[kc + 1]), ab, 0, 0, 0);
                } else {
                    aa = __builtin_amdgcn_mfma_f32_16x16x32_bf16(w0, ahi[kc], aa, 0, 0, 0);
                    ab = __builtin_amdgcn_mfma_f32_16x16x32_bf16(w1, ahi[kc + 1], ab, 0, 0, 0);
                }
            }
            float4v bv = *(const float4v*)(bias1 + (2 * p + hh) * 16 + quad * 4);
#pragma unroll
            for (int r = 0; r < 4; ++r) {
                int n1 = (2 * p + hh) * 16 + quad * 4 + r;
                float v = (n1 < kNH) ? (aa[r] + ab[r] + bv[r]) : 0.f;
                if (v < 0.f) v = 0.f;
                if (H16) {
                    a2[hh * 4 + r] = (short)f2h(v);
                } else {
                    u16 hb = f2bf(v);
                    a2[hh * 4 + r] = (short)hb;
                    a2l[hh * 4 + r] = (short)f2bf(v - bf2f(hb));
                }
            }
        }

#pragma unroll
        for (int nt2 = 0; nt2 < 19; ++nt2) {
            short8 b = load8(B2 + nt2 * 512 + lane * 8);
            if (H16) {
                acc2[nt2] = __builtin_amdgcn_mfma_f32_16x16x32_f16(as_h8(a2), as_h8(b), acc2[nt2], 0, 0, 0);
            } else {
                acc2[nt2] = __builtin_amdgcn_mfma_f32_16x16x32_bf16(a2, b, acc2[nt2], 0, 0, 0);
                acc2[nt2] = __builtin_amdgcn_mfma_f32_16x16x32_bf16(a2l, b, acc2[nt2], 0, 0, 0);
            }
        }
    }

    // ---- epilogue: +bias2 -> D; block-level BN stat reduction ----
    __syncthreads();                 // all waves done reading SMEM buffers
    float* RB = (float*)SMEM;        // reuse: needs 2*4*304 floats (9,728 B)
#pragma unroll
    for (int nt2 = 0; nt2 < 19; ++nt2) {
        int n = nt2 * 16 + r16;
        float s4 = 0.f, q4 = 0.f;
        if (valid && n < kEMB) {
            float bv = bias2[n];
#pragma unroll
            for (int r = 0; r < 4; ++r) {
                float v = acc2[nt2][r] + bv;
                int m = mt * 16 + quad * 4 + r;
                D[(size_t)m * kSA + n] = (u16)(H16 ? f2h(v) : f2bf(v));
                s4 += v; q4 += v * v;
            }
        }
        s4 += __shfl_down(s4, 32); q4 += __shfl_down(q4, 32);
        s4 += __shfl_down(s4, 16); q4 += __shfl_down(q4, 16);
        if (quad == 0) {
            RB[wave * 304 + nt2 * 16 + r16] = s4;
            RB[1216 + wave * 304 + nt2 * 16 + r16] = q4;
        }
    }
    __syncthreads();
    for (int c = tid; c < 304; c += 256) {
        if (c < kEMB) {
            float ss = 0.f, qq = 0.f;
#pragma unroll
            for (int w = 0; w < 4; ++w) {
                ss += RB[w * 304 + c];
                qq += RB[1216 + w * 304 + c];
            }
            atomicAdd(&stats[c], ss);
            atomicAdd(&stats[kEMB + c], qq);
        }
    }
}

// ---- per-graph mean pool (vectorized) with fused final BN -----------------
__device__ inline int lower_bound(const int* a, int n, int key) {
    int lo = 0, hi = n;
    while (lo < hi) { int mid = (lo + hi) >> 1; if (a[mid] < key) lo = mid + 1; else hi = mid; }
    return lo;
}
__global__ __launch_bounds__(64) void pool_kernel(const u16* __restrict__ h2,
                                                  const int* __restrict__ batch,
                                                  const float* __restrict__ stats,
                                                  const float* __restrict__ gam,
                                                  const float* __restrict__ bet,
                                                  void* __restrict__ out,
                                                  const int* __restrict__ flag, int enc) {
    int g = blockIdx.x;
    int lane = threadIdx.x;
    int isf = *flag;
    int start = lower_bound(batch, kN, g);
    int end = lower_bound(batch, kN, g + 1);
    int cnt = end - start;
    float inv = 1.0f / (float)(cnt > 0 ? cnt : 1);
    const float invM = 1.0f / kN;
    for (int cg = lane; cg < 75; cg += 64) {        // 4 channels per group
        int cb = cg * 4;
        float sc[4], sh[4];
#pragma unroll
        for (int jj = 0; jj < 4; ++jj) {
            int c = cb + jj;
            float mu = stats[c] * invM;
            float var = stats[kEMB + c] * invM - mu * mu;
            if (var < 0.f) var = 0.f;
            float rs = rsqrtf(var + kEPS);
            sc[jj] = rs * gam[c];
            sh[jj] = bet[c] - mu * sc[jj];
        }
        float s[4] = {0.f, 0.f, 0.f, 0.f};
        for (int n = start; n < end; ++n) {
            short4v v = *reinterpret_cast<const short4v*>(h2 + (size_t)n * kSA + cb);
#pragma unroll
            for (int jj = 0; jj < 4; ++jj)
                s[jj] += pcvt(v[jj], enc) * sc[jj] + sh[jj];
        }
        if (isf) {
            float4v o;
#pragma unroll
            for (int jj = 0; jj < 4; ++jj) o[jj] = s[jj] * inv;
            *reinterpret_cast<float4v*>((float*)out + (size_t)g * kEMB + cb) = o;
        } else {
            short4v o;
#pragma unroll
            for (int jj = 0; jj < 4; ++jj) o[jj] = (short)f2bf(s[jj] * inv);
            *reinterpret_cast<short4v*>((u16*)out + (size_t)g * kEMB + cb) = o;
        }
    }
}

// ===========================================================================
extern "C" void kernel_launch(void* const* d_in, const int* in_sizes, int n_in,
                              void* d_out, int out_size, void* d_ws, size_t ws_size,
                              hipStream_t stream) {
    const int* x          = (const int*)d_in[0];
    const int* edge_index = (const int*)d_in[1];
    const int* edge_attr  = (const int*)d_in[2];
    const int* batch      = (const int*)d_in[3];
    const void* x_emb1 = d_in[4];
    const void* x_emb2 = d_in[5];
    const void* e1raw  = d_in[6];
    const void* e2raw  = d_in[7];
    const void* W1     = d_in[8];
    const void* b1raw  = d_in[9];
    const void* W2     = d_in[10];
    const void* b2raw  = d_in[11];
    const void* gmraw  = d_in[12];
    const void* btraw  = d_in[13];

    const int* src = edge_index;
    const int* dst = edge_index + kE;

    // Plane encoding: big ws (f32 inputs) -> fp16 planes; else bf16 planes.
    const int enc = (ws_size >= (size_t)250000000) ? 1 : 0;

    // ---- carve workspace (256B aligned) ----
    char* p = (char*)d_ws;
    size_t off = 0;
    auto carve = [&](size_t bytes) {
        void* r = p + off;
        off += (bytes + 255) & ~(size_t)255;
        return r;
    };
    u16* plane0  = (u16*)carve((size_t)kN * kSA * 2);
    u16* plane1  = (u16*)carve((size_t)kN * kSA * 2);
    u16* W1C     = (u16*)carve((size_t)kL * kW1CL * 2);
    u16* W2C     = (u16*)carve((size_t)kL * kW2CL * 2);
    int* row_ptr = (int*)carve((size_t)(kN + 1) * 4);
    int* cursor  = (int*)carve((size_t)kN * 4);
    int* epack   = (int*)carve((size_t)kE * 4);
    float* statsA = (float*)carve(2 * kEMB * 4);
    float* statsB = (float*)carve(2 * kEMB * 4);
    int* bsum    = (int*)carve(512);
    int* ebsum   = (int*)carve(512);
    int* flag    = (int*)carve(256);
    float* parf  = (float*)carve((size_t)57900 * 4);   // canonical f32 params

    float* emb1  = parf + 0;       // 36000
    float* emb2  = parf + 36000;   // 900
    float* e1    = parf + 36900;   // 9000
    float* e2    = parf + 45900;   // 4500
    float* b1    = parf + 50400;   // 3000
    float* b2    = parf + 53400;   // 1500
    float* gamma = parf + 54900;   // 1500
    float* beta  = parf + 56400;   // 1500

    // ---- dtype detect + canonicalize params to f32 ----
    detect_kernel<<<1, 64, 0, stream>>>((const u16*)W1, flag);
    cvt_kernel<<<(36000 + 255) / 256, 256, 0, stream>>>(x_emb1, emb1, 36000, flag);
    cvt_kernel<<<(900 + 255) / 256, 256, 0, stream>>>(x_emb2, emb2, 900, flag);
    cvt_kernel<<<(9000 + 255) / 256, 256, 0, stream>>>(e1raw, e1, 9000, flag);
    cvt_kernel<<<(4500 + 255) / 256, 256, 0, stream>>>(e2raw, e2, 4500, flag);
    cvt_kernel<<<(3000 + 255) / 256, 256, 0, stream>>>(b1raw, b1, 3000, flag);
    cvt_kernel<<<(1500 + 255) / 256, 256, 0, stream>>>(b2raw, b2, 1500, flag);
    cvt_kernel<<<(1500 + 255) / 256, 256, 0, stream>>>(gmraw, gamma, 1500, flag);
    cvt_kernel<<<(1500 + 255) / 256, 256, 0, stream>>>(btraw, beta, 1500, flag);

    // ---- weight repack to chunk order (fp16 when enc, else bf16) ----
    {
        int n1 = kL * kW1CL;
        w1t_kernel<<<(n1 + 255) / 256, 256, 0, stream>>>(W1, W1C, flag, enc);
        int n2 = kL * kW2CL;
        w2t_kernel<<<(n2 + 255) / 256, 256, 0, stream>>>(W2, W2C, flag, enc);
    }

    // ---- embedding into plane0 (vectorized) ----
    embed_kernel<<<(kN * 76 + 255) / 256, 256, 0, stream>>>(x, emb1, emb2, plane0, enc);

    // ---- CSR build (multi-block scan) ----
    zero_int_kernel<<<(kN + 1 + 255) / 256, 256, 0, stream>>>(row_ptr, kN + 1);
    zero_int_kernel<<<(kN + 255) / 256, 256, 0, stream>>>(cursor, kN);
    count_kernel<<<(kE + 255) / 256, 256, 0, stream>>>(dst, row_ptr);
    const int nb = (kN + 1023) / 1024;   // 98
    scan1_kernel<<<nb, 1024, 0, stream>>>(row_ptr + 1, bsum, kN);
    scan2_kernel<<<1, 128, 0, stream>>>(bsum, ebsum, nb);
    scan3_kernel<<<(kN + 255) / 256, 256, 0, stream>>>(row_ptr + 1, ebsum, row_ptr, kN);
    scatter_kernel<<<(kE + 255) / 256, 256, 0, stream>>>(src, dst, edge_attr, row_ptr,
                                                         cursor, epack);

    // ---- layers: aggregate(cur -> oth), mlp(oth -> cur) ----
    const int mlp_blocks = (kN / 16 + 3) / 4;   // 1563 (4 m-tiles per block)
    const int agg_blocks = (kN + 15) / 16;      // 6250 (16 nodes per block)
    u16* cur = plane0;
    u16* oth = plane1;
    float* stats_prev = statsA;   // unused at l=0
    for (int l = 0; l < kL; ++l) {
        float* stats_cur = (l % 2 == 0) ? statsA : statsB;
        const float* gam_prev = gamma + (l > 0 ? (l - 1) : 0) * kEMB;
        const float* bet_prev = beta + (l > 0 ? (l - 1) : 0) * kEMB;
        aggregate_kernel<<<agg_blocks, 256, 0, stream>>>(
            cur, row_ptr, epack, e1 + l * 6 * kEMB, e2 + l * 3 * kEMB,
            (l > 0) ? stats_prev : stats_cur, gam_prev, bet_prev,
            stats_cur, oth, (l > 0) ? 1 : 0, enc);
        if (enc)
            mlp_kernel<1><<<mlp_blocks, 256, 0, stream>>>(
                oth, cur, W1C + (size_t)l * kW1CL, b1 + l * kNH,
                W2C + (size_t)l * kW2CL, b2 + l * kEMB, stats_cur);
        else
            mlp_kernel<0><<<mlp_blocks, 256, 0, stream>>>(
                oth, cur, W1C + (size_t)l * kW1CL, b1 + l * kNH,
                W2C + (size_t)l * kW2CL, b2 + l * kEMB, stats_cur);
        stats_prev = stats_cur;
    }

    // ---- pooling with fused final BN (stats_prev = layer 4's stats) ----
    pool_kernel<<<kG, 64, 0, stream>>>(cur, batch, stats_prev, gamma + 4 * kEMB,
                                       beta + 4 * kEMB, d_out, flag, enc);
}